// Round 1
// baseline (5677.144 us; speedup 1.0000x reference)
//
#include <hip/hip_runtime.h>
#include <hip/hip_bf16.h>
#include <hip/hip_fp16.h>
#include <stdint.h>

// Problem dims
#define BB 128
#define TT 512
#define HH 256
#define VV 29
#define NSTEP 63
#define BT (BB*TT)
#define CHUNK 64   // layer-1 time chunk

typedef _Float16 f16;
typedef _Float16 f16x2 __attribute__((ext_vector_type(2)));
typedef _Float16 f16x8 __attribute__((ext_vector_type(8)));
typedef float f32x4 __attribute__((ext_vector_type(4)));

static __device__ __forceinline__ float fdot2u(uint32_t a, uint32_t b, float c) {
  return __builtin_amdgcn_fdot2(__builtin_bit_cast(f16x2, a),
                                __builtin_bit_cast(f16x2, b), c, false);
}
static __device__ __forceinline__ float sigm_(float x) {
  return 1.0f / (1.0f + __expf(-x));
}

// ---------------- fp32 -> f16 convert ----------------
__global__ void k_cvt(const float* __restrict__ s, f16* __restrict__ d, int n) {
  int i = blockIdx.x * 256 + threadIdx.x;
  if (i < n) d[i] = (f16)s[i];
}

// ---------------- persistent GRU scan: 1 WG per (batch, dir) ----------------
template<int LAYER>
__global__ __launch_bounds__(512, 2)
void k_scan(const float* __restrict__ x,        // L0: (B,T,2)
            const f16* __restrict__ gi,         // L1: (B,nsteps,1536) chunk-local
            const uint32_t* __restrict__ whh,   // (2,768,128) as half2
            const float* __restrict__ wih0,     // L0: (2,768,2)
            const float* __restrict__ bih,      // L0: (2,768)
            const float* __restrict__ bhh,      // (2,768)
            f16* __restrict__ y,                // (B,T,512) [t][dir*256+p]
            float* __restrict__ hstate,         // (2,B,256) f32
            int t0, int nsteps)
{
  const int wg = blockIdx.x, b = wg >> 1, dir = wg & 1;
  const int tid = threadIdx.x, pair = tid >> 1, half = tid & 1;
  __shared__ __align__(16) uint4 hv4[32];   // h as f16[256]

  uint4 w0[16], w1[16], w2[16];
  {
    const uint32_t* wp = whh + (size_t)dir * 768 * 128;
    const uint4* r0 = (const uint4*)(wp + (size_t)pair * 128 + half * 64);
    const uint4* r1 = (const uint4*)(wp + (size_t)(pair + 256) * 128 + half * 64);
    const uint4* r2 = (const uint4*)(wp + (size_t)(pair + 512) * 128 + half * 64);
#pragma unroll
    for (int i = 0; i < 16; i++) { w0[i] = r0[i]; w1[i] = r1[i]; w2[i] = r2[i]; }
  }
  const float bh0 = bhh[dir * 768 + pair];
  const float bh1 = bhh[dir * 768 + pair + 256];
  const float bh2 = bhh[dir * 768 + pair + 512];
  float bi0 = 0, bi1 = 0, bi2 = 0;
  float wi00 = 0, wi01 = 0, wi10 = 0, wi11 = 0, wi20 = 0, wi21 = 0;
  if (LAYER == 0) {
    bi0 = bih[dir * 768 + pair];
    bi1 = bih[dir * 768 + pair + 256];
    bi2 = bih[dir * 768 + pair + 512];
    wi00 = wih0[(dir * 768 + pair) * 2 + 0];
    wi01 = wih0[(dir * 768 + pair) * 2 + 1];
    wi10 = wih0[(dir * 768 + pair + 256) * 2 + 0];
    wi11 = wih0[(dir * 768 + pair + 256) * 2 + 1];
    wi20 = wih0[(dir * 768 + pair + 512) * 2 + 0];
    wi21 = wih0[(dir * 768 + pair + 512) * 2 + 1];
  }
  float* hs = hstate + ((size_t)dir * BB + b) * 256;
  float hreg = hs[pair];
  if (tid < 128) {
    f16x2 p2; p2[0] = (f16)hs[2 * tid]; p2[1] = (f16)hs[2 * tid + 1];
    ((uint32_t*)hv4)[tid] = __builtin_bit_cast(uint32_t, p2);
  }
  __syncthreads();

  const uint4* hw = hv4 + half * 16;
  for (int s = 0; s < nsteps; ++s) {
    const int t = dir ? (TT - 1 - t0 - s) : (t0 + s);
    float gr, gz, gn;
    if (LAYER == 0) {
      float x0 = x[((size_t)b * TT + t) * 2 + 0];
      float x1 = x[((size_t)b * TT + t) * 2 + 1];
      gr = wi00 * x0 + wi01 * x1 + bi0;
      gz = wi10 * x0 + wi11 * x1 + bi1;
      gn = wi20 * x0 + wi21 * x1 + bi2;
    } else {
      const f16* g = gi + ((size_t)b * nsteps + s) * 1536 + dir * 768 + pair;
      gr = (float)g[0]; gz = (float)g[256]; gn = (float)g[512];
    }
    float a0 = 0.f, a1 = 0.f, a2 = 0.f;
#pragma unroll
    for (int j = 0; j < 16; ++j) {
      uint4 hh = hw[j];
      a0 = fdot2u(w0[j].x, hh.x, a0); a0 = fdot2u(w0[j].y, hh.y, a0);
      a0 = fdot2u(w0[j].z, hh.z, a0); a0 = fdot2u(w0[j].w, hh.w, a0);
      a1 = fdot2u(w1[j].x, hh.x, a1); a1 = fdot2u(w1[j].y, hh.y, a1);
      a1 = fdot2u(w1[j].z, hh.z, a1); a1 = fdot2u(w1[j].w, hh.w, a1);
      a2 = fdot2u(w2[j].x, hh.x, a2); a2 = fdot2u(w2[j].y, hh.y, a2);
      a2 = fdot2u(w2[j].z, hh.z, a2); a2 = fdot2u(w2[j].w, hh.w, a2);
    }
    a0 += __shfl_xor(a0, 1);
    a1 += __shfl_xor(a1, 1);
    a2 += __shfl_xor(a2, 1);

    float r = sigm_(gr + a0 + bh0);
    float z = sigm_(gz + a1 + bh1);
    float n = tanhf(gn + r * (a2 + bh2));
    float hn = (1.0f - z) * n + z * hreg;
    hreg = hn;
    if (half == 0) y[((size_t)b * TT + t) * 512 + dir * 256 + pair] = (f16)hn;
    __syncthreads();  // all hv reads done
    if (half == 0) ((f16*)hv4)[pair] = (f16)hn;
    __syncthreads();  // hv updated
  }
  if (half == 0) hs[pair] = hreg;
}

// ---------------- f16 MFMA GEMM: C = Arows @ Bt^T + bias ---------------------
__global__ __launch_bounds__(256)
void k_gemm(const f16* __restrict__ A, const f16* __restrict__ Bt,
            f16* __restrict__ C, const float* __restrict__ bias,
            int K, int shift, long bstride, int inner, int ldc, int coloff)
{
  const int m0 = blockIdx.x * 64, n0 = blockIdx.y * 64;
  const int tid = threadIdx.x, lane = tid & 63, wv = tid >> 6;
  __shared__ __align__(16) f16 As[64 * 40];
  __shared__ __align__(16) f16 Bs[64 * 40];
  f32x4 acc[4] = {{0,0,0,0},{0,0,0,0},{0,0,0,0},{0,0,0,0}};
  const int lrow = tid >> 2, lseg = tid & 3;
  const int ml = lane & 15, quad = lane >> 4;
  const int r = m0 + lrow;
  const f16* arow = A + (long)(r >> shift) * bstride
                      + (long)(r & ((1 << shift) - 1)) * inner;
  const f16* brow = Bt + (size_t)(n0 + lrow) * K;
  for (int k0 = 0; k0 < K; k0 += 32) {
    uint4 av = *(const uint4*)(arow + k0 + lseg * 8);
    uint4 bv = *(const uint4*)(brow + k0 + lseg * 8);
    __syncthreads();
    *(uint4*)(As + lrow * 40 + lseg * 8) = av;
    *(uint4*)(Bs + lrow * 40 + lseg * 8) = bv;
    __syncthreads();
    f16x8 af = *(const f16x8*)(As + (wv * 16 + ml) * 40 + quad * 8);
#pragma unroll
    for (int ns = 0; ns < 4; ++ns) {
      f16x8 bf = *(const f16x8*)(Bs + (ns * 16 + ml) * 40 + quad * 8);
      acc[ns] = __builtin_amdgcn_mfma_f32_16x16x32_f16(af, bf, acc[ns], 0, 0, 0);
    }
  }
#pragma unroll
  for (int ns = 0; ns < 4; ++ns) {
#pragma unroll
    for (int rr = 0; rr < 4; ++rr) {
      int row = m0 + wv * 16 + quad * 4 + rr;
      int col = n0 + ns * 16 + ml;
      float v = acc[ns][rr];
      if (bias) v += bias[col];
      C[(size_t)row * ldc + coloff + col] = (f16)v;
    }
  }
}

// ---------------- gi0[v][row] = dWih0 @ emb[v] + dbih  (29 x 768, f32) -------
__global__ void k_gi0(const float* __restrict__ dWih0, const float* __restrict__ dbih,
                      const float* __restrict__ emb, float* __restrict__ gi0) {
  int i = blockIdx.x * 256 + threadIdx.x;
  if (i >= VV * 768) return;
  int v = i / 768, row = i - v * 768;
  float a = dbih[row];
#pragma unroll
  for (int e = 0; e < 8; ++e) a += dWih0[row * 8 + e] * emb[v * 8 + e];
  gi0[i] = a;
}

// ---------------- enc (B,512,256) -> encT (B,256,512), LDS-tiled -------------
__global__ __launch_bounds__(256)
void k_transpose(const f16* __restrict__ enc, f16* __restrict__ encT) {
  __shared__ f16 tile[64][64];   // XOR-swizzled columns, no pad needed
  const int b = blockIdx.x, t0 = blockIdx.y * 64, c0 = blockIdx.z * 64;
  const int tid = threadIdx.x;
  const int r = tid >> 3, c8 = (tid & 7) * 8;
#pragma unroll
  for (int p = 0; p < 2; ++p) {
    int row = p * 32 + r;
    uint4 v = *(const uint4*)(enc + ((size_t)b * 512 + t0 + row) * 256 + c0 + c8);
    *(uint4*)(&tile[row][c8 ^ ((row >> 3) * 8)]) = v;
  }
  __syncthreads();
  const int t8 = (tid & 7) * 8;
  const int sw = (tid & 7) * 8;   // (t8+j)>>3 == tid&7 for j<8
#pragma unroll
  for (int p = 0; p < 2; ++p) {
    int cc = p * 32 + r;
    int ccs = cc ^ sw;
    f16 tmp[8];
#pragma unroll
    for (int j = 0; j < 8; ++j) tmp[j] = tile[t8 + j][ccs];
    *(uint4*)(encT + ((size_t)b * 256 + c0 + cc) * 512 + t0 + t8) = *(uint4*)tmp;
  }
}

// ---------------- matvec helpers (2-way k-split over lane pairs) -------------
// 3 rows (row0, +256, +512) of W (768x256 f16), half-k (128 elems at koff)
static __device__ __forceinline__ void mv3h(const f16* __restrict__ W, int row0, int koff,
                                            const f16* __restrict__ hsh,
                                            float& g0, float& g1, float& g2) {
  const uint4* w0 = (const uint4*)(W + (size_t)row0 * 256 + koff);
  const uint4* w1 = (const uint4*)(W + (size_t)(row0 + 256) * 256 + koff);
  const uint4* w2 = (const uint4*)(W + (size_t)(row0 + 512) * 256 + koff);
  const uint4* hv = (const uint4*)(hsh + koff);
#pragma unroll 2
  for (int kc = 0; kc < 4; ++kc) {
    uint4 aq[4], bq[4], cq[4], hq[4];
#pragma unroll
    for (int j = 0; j < 4; ++j) {
      aq[j] = w0[4 * kc + j]; bq[j] = w1[4 * kc + j];
      cq[j] = w2[4 * kc + j]; hq[j] = hv[4 * kc + j];
    }
#pragma unroll
    for (int j = 0; j < 4; ++j) {
      g0 = fdot2u(aq[j].x, hq[j].x, g0); g0 = fdot2u(aq[j].y, hq[j].y, g0);
      g0 = fdot2u(aq[j].z, hq[j].z, g0); g0 = fdot2u(aq[j].w, hq[j].w, g0);
      g1 = fdot2u(bq[j].x, hq[j].x, g1); g1 = fdot2u(bq[j].y, hq[j].y, g1);
      g1 = fdot2u(bq[j].z, hq[j].z, g1); g1 = fdot2u(bq[j].w, hq[j].w, g1);
      g2 = fdot2u(cq[j].x, hq[j].x, g2); g2 = fdot2u(cq[j].y, hq[j].y, g2);
      g2 = fdot2u(cq[j].z, hq[j].z, g2); g2 = fdot2u(cq[j].w, hq[j].w, g2);
    }
  }
}
// half-row dot (128 elems at koff) of one W row vs LDS h
static __device__ __forceinline__ float mv1h(const f16* __restrict__ W, int koff,
                                             const f16* __restrict__ hsh) {
  const uint4* w = (const uint4*)(W + koff);
  const uint4* hv = (const uint4*)(hsh + koff);
  float g0 = 0.f, g1 = 0.f;
#pragma unroll
  for (int kc = 0; kc < 2; ++kc) {
    uint4 aq[8], hq[8];
#pragma unroll
    for (int j = 0; j < 8; ++j) { aq[j] = w[8 * kc + j]; hq[j] = hv[8 * kc + j]; }
#pragma unroll
    for (int j = 0; j < 8; j += 2) {
      g0 = fdot2u(aq[j].x, hq[j].x, g0); g0 = fdot2u(aq[j].y, hq[j].y, g0);
      g0 = fdot2u(aq[j].z, hq[j].z, g0); g0 = fdot2u(aq[j].w, hq[j].w, g0);
      g1 = fdot2u(aq[j+1].x, hq[j+1].x, g1); g1 = fdot2u(aq[j+1].y, hq[j+1].y, g1);
      g1 = fdot2u(aq[j+1].z, hq[j+1].z, g1); g1 = fdot2u(aq[j+1].w, hq[j+1].w, g1);
    }
  }
  return g0 + g1;
}
// full-row dot (256 elems) vs LDS h, 2 accumulators
static __device__ __forceinline__ float mv1f(const f16* __restrict__ W,
                                             const f16* __restrict__ hsh) {
  const uint4* w = (const uint4*)W;
  const uint4* hv = (const uint4*)hsh;
  float g0 = 0.f, g1 = 0.f;
#pragma unroll 2
  for (int kc = 0; kc < 4; ++kc) {
    uint4 aq[8], hq[8];
#pragma unroll
    for (int j = 0; j < 8; ++j) { aq[j] = w[8 * kc + j]; hq[j] = hv[8 * kc + j]; }
#pragma unroll
    for (int j = 0; j < 8; j += 2) {
      g0 = fdot2u(aq[j].x, hq[j].x, g0); g0 = fdot2u(aq[j].y, hq[j].y, g0);
      g0 = fdot2u(aq[j].z, hq[j].z, g0); g0 = fdot2u(aq[j].w, hq[j].w, g0);
      g1 = fdot2u(aq[j+1].x, hq[j+1].x, g1); g1 = fdot2u(aq[j+1].y, hq[j+1].y, g1);
      g1 = fdot2u(aq[j+1].z, hq[j+1].z, g1); g1 = fdot2u(aq[j+1].w, hq[j+1].w, g1);
    }
  }
  return g0 + g1;
}

// ---------------- persistent decoder: 1 WG (512 thr) per batch, 63 steps -----
__global__ __launch_bounds__(512, 2)
void k_decoder(const f16* __restrict__ dwhh,   // (2,768,256)
               const f16* __restrict__ dwih1,  // (768,256)
               const f16* __restrict__ qw,     // (256,256)
               const f16* __restrict__ outw,   // (29,256)
               const f16* __restrict__ enc,    // (B,512,256)
               const f16* __restrict__ encT,   // (B,256,512)
               const float* __restrict__ gi0,  // (29,768) input gates per token
               const float* __restrict__ dbih, // (2,768)
               const float* __restrict__ dbhh, // (2,768)
               const float* __restrict__ qb, const float* __restrict__ outb,
               const float* __restrict__ hs0, const float* __restrict__ hs1,
               const int* __restrict__ tseq,
               float* __restrict__ out)
{
  const int b = blockIdx.x, tid = threadIdx.x;
  const int pair = tid >> 1, half = tid & 1, koff = half * 128;
  __shared__ __align__(16) f16 h0buf[2][256];
  __shared__ __align__(16) f16 h1buf[2][256];
  __shared__ __align__(16) f16 qsh[256];
  __shared__ __align__(16) float sc[512];
  __shared__ float red[8], red2[8];
  __shared__ __align__(16) float cpart[2][256];
  __shared__ __align__(16) float hc[256];
  __shared__ float lg[VV];

  // hoisted per-thread constants (live across all 63 steps)
  const float bh00 = dbhh[pair], bh01 = dbhh[pair + 256], bh02 = dbhh[pair + 512];
  const float bi10 = dbih[768 + pair], bi11 = dbih[768 + pair + 256], bi12 = dbih[768 + pair + 512];
  const float bh10 = dbhh[768 + pair], bh11 = dbhh[768 + pair + 256], bh12 = dbhh[768 + pair + 512];
  const float qbv = qb[pair];
  const f16* dwhh1 = dwhh + (size_t)768 * 256;
  float h0reg = hs0[b * 256 + pair] + hs0[32768 + b * 256 + pair];
  float h1reg = hs1[b * 256 + pair] + hs1[32768 + b * 256 + pair];
  // logits weights (constant): 2 uint4 per (v,kseg) thread
  const int lv_ = tid >> 4, lk_ = tid & 15;
  uint4 ow0 = {0,0,0,0}, ow1 = {0,0,0,0}; float outbv = 0.f;
  if (tid < VV * 16) {
    const uint4* owp = (const uint4*)(outw + (size_t)lv_ * 256 + lk_ * 16);
    ow0 = owp[0]; ow1 = owp[1];
    outbv = outb[lv_];
  }
  if (tid < 256) {
    h0buf[0][tid] = (f16)(hs0[b * 256 + tid] + hs0[32768 + b * 256 + tid]);
    h1buf[0][tid] = (f16)(hs1[b * 256 + tid] + hs1[32768 + b * 256 + tid]);
  }
  int tok = tseq[b * 64];          // broadcast load, every thread
  __syncthreads();

  for (int s = 0; s < NSTEP; ++s) {
    const int cur = s & 1, nxt = cur ^ 1;
    // ---- cell0: input gates from precomputed gi0 table ----
    const float* giP = gi0 + tok * 768;
    float i0 = giP[pair], i1 = giP[pair + 256], i2 = giP[pair + 512];
    float g0 = 0.f, g1 = 0.f, g2 = 0.f;
    mv3h(dwhh, pair, koff, h0buf[cur], g0, g1, g2);
    g0 += __shfl_xor(g0, 1); g1 += __shfl_xor(g1, 1); g2 += __shfl_xor(g2, 1);
    {
      float r = sigm_(i0 + g0 + bh00);
      float z = sigm_(i1 + g1 + bh01);
      float n = tanhf(i2 + r * (g2 + bh02));
      h0reg = (1.f - z) * n + z * h0reg;
    }
    if (half == 0) h0buf[nxt][pair] = (f16)h0reg;
    __syncthreads();             // B1: h0 new visible

    // ---- cell1 ----
    float a0 = 0.f, a1 = 0.f, a2 = 0.f, c0 = 0.f, c1 = 0.f, c2 = 0.f;
    mv3h(dwih1, pair, koff, h0buf[nxt], a0, a1, a2);
    mv3h(dwhh1, pair, koff, h1buf[cur], c0, c1, c2);
    a0 += __shfl_xor(a0, 1); a1 += __shfl_xor(a1, 1); a2 += __shfl_xor(a2, 1);
    c0 += __shfl_xor(c0, 1); c1 += __shfl_xor(c1, 1); c2 += __shfl_xor(c2, 1);
    {
      float r = sigm_(a0 + bi10 + c0 + bh10);
      float z = sigm_(a1 + bi11 + c1 + bh11);
      float n = tanhf(a2 + bi12 + r * (c2 + bh12));
      h1reg = (1.f - z) * n + z * h1reg;
    }
    if (half == 0) h1buf[nxt][pair] = (f16)h1reg;
    __syncthreads();             // B2: h1 new visible

    // ---- q = qW @ h1' + qb (2-way split) ----
    {
      float qv = mv1h(qw + (size_t)pair * 256, koff, h1buf[nxt]);
      qv += __shfl_xor(qv, 1);
      if (half == 0) qsh[pair] = (f16)(qv + qbv);
    }
    __syncthreads();             // B3: qsh visible

    // ---- scores: one enc row per thread, kept in register ----
    float sv = mv1f(enc + ((size_t)b * 512 + tid) * 256, qsh);

    // ---- softmax over 512 (register value, shfl + 8-entry LDS red) ----
    float mloc = sv;
#pragma unroll
    for (int off = 32; off; off >>= 1) mloc = fmaxf(mloc, __shfl_xor(mloc, off));
    if ((tid & 63) == 0) red[tid >> 6] = mloc;
    __syncthreads();             // B4
    float m = red[0];
#pragma unroll
    for (int w = 1; w < 8; ++w) m = fmaxf(m, red[w]);
    float ex = __expf(sv - m);
    sc[tid] = ex;
    float lloc = ex;
#pragma unroll
    for (int off = 32; off; off >>= 1) lloc += __shfl_xor(lloc, off);
    if ((tid & 63) == 0) red2[tid >> 6] = lloc;
    __syncthreads();             // B5: ex in sc + red2 visible
    float l = red2[0] + red2[1] + red2[2] + red2[3]
            + red2[4] + red2[5] + red2[6] + red2[7];

    // ---- ctx: transposed enc, contiguous uint4 rows, 2-way t-split ----
    {
      const int c = tid & 255, th = tid >> 8;
      const uint4* ev = (const uint4*)(encT + ((size_t)b * 256 + c) * 512 + th * 256);
      const float4* wv = (const float4*)(sc + th * 256);
      float acc0 = 0.f, acc1 = 0.f;
#pragma unroll 4
      for (int i = 0; i < 32; ++i) {
        uint4 v = ev[i];
        float4 wa = wv[2 * i], wb = wv[2 * i + 1];
        f16x2 p0 = __builtin_bit_cast(f16x2, v.x);
        f16x2 p1 = __builtin_bit_cast(f16x2, v.y);
        f16x2 p2 = __builtin_bit_cast(f16x2, v.z);
        f16x2 p3 = __builtin_bit_cast(f16x2, v.w);
        acc0 += wa.x*(float)p0[0] + wa.y*(float)p0[1] + wa.z*(float)p1[0] + wa.w*(float)p1[1];
        acc1 += wb.x*(float)p2[0] + wb.y*(float)p2[1] + wb.z*(float)p3[0] + wb.w*(float)p3[1];
      }
      cpart[th][c] = acc0 + acc1;
    }
    __syncthreads();             // B6: cpart visible
    if (tid < 256) hc[tid] = (cpart[0][tid] + cpart[1][tid]) / l + (float)h1buf[nxt][tid];
    __syncthreads();             // B7: hc visible

    // ---- logits (29x256, 16-way k-split, weights in registers) ----
    if (tid < VV * 16) {
      const float4* hv = (const float4*)(hc + lk_ * 16);
      float4 ha = hv[0], hb = hv[1], hcv = hv[2], hd = hv[3];
      f16x2 q0 = __builtin_bit_cast(f16x2, ow0.x);
      f16x2 q1 = __builtin_bit_cast(f16x2, ow0.y);
      f16x2 q2 = __builtin_bit_cast(f16x2, ow0.z);
      f16x2 q3 = __builtin_bit_cast(f16x2, ow0.w);
      f16x2 q4 = __builtin_bit_cast(f16x2, ow1.x);
      f16x2 q5 = __builtin_bit_cast(f16x2, ow1.y);
      f16x2 q6 = __builtin_bit_cast(f16x2, ow1.z);
      f16x2 q7 = __builtin_bit_cast(f16x2, ow1.w);
      float acc = (float)q0[0]*ha.x + (float)q0[1]*ha.y + (float)q1[0]*ha.z + (float)q1[1]*ha.w
                + (float)q2[0]*hb.x + (float)q2[1]*hb.y + (float)q3[0]*hb.z + (float)q3[1]*hb.w
                + (float)q4[0]*hcv.x + (float)q4[1]*hcv.y + (float)q5[0]*hcv.z + (float)q5[1]*hcv.w
                + (float)q6[0]*hd.x + (float)q6[1]*hd.y + (float)q7[0]*hd.z + (float)q7[1]*hd.w;
      acc += __shfl_xor(acc, 1); acc += __shfl_xor(acc, 2);
      acc += __shfl_xor(acc, 4); acc += __shfl_xor(acc, 8);
      if (lk_ == 0) {
        float lvv = acc + outbv;
        lg[lv_] = lvv;
        out[((size_t)b * NSTEP + s) * VV + lv_] = lvv;
      }
    }
    __syncthreads();             // B8: lg visible

    // ---- argmax: replicated in every wave (no extra barrier) ----
    {
      const int lane = tid & 63;
      float val = (lane < VV) ? lg[lane] : -3.4e38f;
      int bi = lane;
#pragma unroll
      for (int off = 32; off; off >>= 1) {
        float ov = __shfl_xor(val, off);
        int oi = __shfl_xor(bi, off);
        if (ov > val || (ov == val && oi < bi)) { val = ov; bi = oi; }
      }
      tok = bi;
    }
  }

  // final hidden: out[233856 + {0,1}*32768 + b*256 + p]
  if (tid < 256) {
    out[233856 + b * 256 + tid] = (float)h0buf[NSTEP & 1][tid];
    out[233856 + 32768 + b * 256 + tid] = (float)h1buf[NSTEP & 1][tid];
  }
}

extern "C" void kernel_launch(void* const* d_in, const int* in_sizes, int n_in,
                              void* d_out, int out_size, void* d_ws, size_t ws_size,
                              hipStream_t stream) {
  (void)in_sizes; (void)n_in; (void)out_size; (void)ws_size;
  const float* x     = (const float*)d_in[0];
  const int*   tseq  = (const int*)d_in[1];
  const float* eWih0 = (const float*)d_in[2];
  const float* eWhh0 = (const float*)d_in[3];
  const float* ebih0 = (const float*)d_in[4];
  const float* ebhh0 = (const float*)d_in[5];
  const float* eWih1 = (const float*)d_in[6];
  const float* eWhh1 = (const float*)d_in[7];
  const float* ebih1 = (const float*)d_in[8];
  const float* ebhh1 = (const float*)d_in[9];
  const float* e2dW  = (const float*)d_in[10];
  const float* e2db  = (const float*)d_in[11];
  const float* dWih0 = (const float*)d_in[12];
  const float* dWih1 = (const float*)d_in[13];
  const float* dWhh  = (const float*)d_in[14];
  const float* dbih  = (const float*)d_in[15];
  const float* dbhh  = (const float*)d_in[16];
  const float* qW    = (const float*)d_in[17];
  const float* qb    = (const float*)d_in[18];
  const float* outW  = (const float*)d_in[19];
  const float* outb  = (const float*)d_in[20];
  const float* emb   = (const float*)d_in[21];

  // ---- workspace ledger ----
  uint8_t* ws = (uint8_t*)d_ws;
  size_t o = 0;
  auto take = [&](size_t bytes) -> void* {
    void* p = ws + o;
    o += (bytes + 255) & ~(size_t)255;
    return p;
  };
  f16* whh0_16  = (f16*)take((size_t)2 * 768 * 256 * 2);
  f16* whh1_16  = (f16*)take((size_t)2 * 768 * 256 * 2);
  f16* wih1_16  = (f16*)take((size_t)2 * 768 * 512 * 2);
  f16* e2d_16   = (f16*)take((size_t)256 * 512 * 2);
  f16* qw_16    = (f16*)take((size_t)256 * 256 * 2);
  f16* outw_16  = (f16*)take((size_t)29 * 256 * 2);
  f16* dwih1_16 = (f16*)take((size_t)768 * 256 * 2);
  f16* dwhh_16  = (f16*)take((size_t)2 * 768 * 256 * 2);
  f16* y0   = (f16*)take((size_t)BT * 512 * 2);          // enc aliases later
  f16* y1   = (f16*)take((size_t)BT * 512 * 2);          // encT aliases later
  f16* gi   = (f16*)take((size_t)BB * CHUNK * 1536 * 2); // rolling chunk
  float* hs0 = (float*)take((size_t)2 * BB * 256 * 4);
  float* hs1 = (float*)take((size_t)2 * BB * 256 * 4);
  float* gi0 = (float*)take((size_t)VV * 768 * 4);
  f16* enc  = y0;  // alias: y0 dead after last gi chunk GEMM
  f16* encT = y1;  // alias: y1 dead after final e2d GEMM

  hipMemsetAsync(hs0, 0, (size_t)2 * BB * 256 * 4, stream);
  hipMemsetAsync(hs1, 0, (size_t)2 * BB * 256 * 4, stream);

  auto cvt = [&](const float* s, f16* d, int n) {
    k_cvt<<<(n + 255) / 256, 256, 0, stream>>>(s, d, n);
  };
  cvt(eWhh0, whh0_16, 2 * 768 * 256);
  cvt(eWhh1, whh1_16, 2 * 768 * 256);
  cvt(eWih1, wih1_16, 2 * 768 * 512);
  cvt(e2dW,  e2d_16,  256 * 512);
  cvt(qW,    qw_16,   256 * 256);
  cvt(outW,  outw_16, 29 * 256);
  cvt(dWih1, dwih1_16, 768 * 256);
  cvt(dWhh,  dwhh_16, 2 * 768 * 256);
  k_gi0<<<(VV * 768 + 255) / 256, 256, 0, stream>>>(dWih0, dbih, emb, gi0);

  // encoder layer 0 (both dirs, full T; gi inline since IN=2)
  k_scan<0><<<256, 512, 0, stream>>>(x, nullptr, (const uint32_t*)whh0_16,
                                     eWih0, ebih0, ebhh0, y0, hs0, 0, TT);

  // encoder layer 1: time-chunked gi GEMM + scan
  const long BSTR = (long)TT * 512;  // per-b element stride in y0
  for (int c = 0; c < TT / CHUNK; ++c) {
    const int t0 = c * CHUNK;
    k_gemm<<<dim3(BB * CHUNK / 64, 12), 256, 0, stream>>>(
        y0 + (size_t)t0 * 512, wih1_16, gi, ebih1,
        512, 6, BSTR, 512, 1536, 0);
    k_gemm<<<dim3(BB * CHUNK / 64, 12), 256, 0, stream>>>(
        y0 + (size_t)(TT - 1 - t0) * 512, wih1_16 + (size_t)768 * 512, gi, ebih1 + 768,
        512, 6, BSTR, -512, 1536, 768);
    k_scan<1><<<256, 512, 0, stream>>>(nullptr, gi, (const uint32_t*)whh1_16,
                                       nullptr, nullptr, ebhh1, y1, hs1, t0, CHUNK);
  }

  // enc = y1 @ e2d^T + b   (writes into y0's region)
  k_gemm<<<dim3(BT / 64, 4), 256, 0, stream>>>(y1, e2d_16, enc, e2db,
                                               512, 30, 0, 512, 256, 0);

  // encT = transpose(enc) into y1's region (y1 dead now)
  k_transpose<<<dim3(BB, 8, 4), 256, 0, stream>>>(enc, encT);

  // persistent decoder: one 512-thread WG per batch element, all 63 steps
  k_decoder<<<BB, 512, 0, stream>>>(dwhh_16, dwih1_16, qw_16, outw_16,
                                    enc, encT, gi0, dbih, dbhh, qb, outb,
                                    hs0, hs1, tseq, (float*)d_out);
}